// Round 8
// baseline (582.288 us; speedup 1.0000x reference)
//
#include <hip/hip_runtime.h>

#define NN 100000
#define NE 800000
// D = 160, 2D = 320, F = 128

typedef _Float16 half8 __attribute__((ext_vector_type(8)));
typedef _Float16 half4 __attribute__((ext_vector_type(4)));
typedef float floatx4 __attribute__((ext_vector_type(4)));

#define LDB(Wf, f) (*(const half8*)&(Wf)[(f) * 512])

// ---------------------------------------------------------------- zero
__global__ __launch_bounds__(256) void k_zero(float4* __restrict__ p, int n4) {
  int i = blockIdx.x * 256 + threadIdx.x;
  if (i < n4) p[i] = make_float4(0.f, 0.f, 0.f, 0.f);
}

// ---------------------------------------------------------------- fragment-pack all weights
// Fragment f=(kk,i): 1KB chunk, lane reads 16B at dst[f*1024 + lane*16].
// b for lane(mrow,quad) of frag (kk,i) = W[i*16+mrow][kk*32+quad*8 .. +8].
// Segments: We 32 frags | Wo 40 | Wu 2x100 | Wp 2x2x50.  472 frags x 64 lanes.
__global__ __launch_bounds__(256) void k_pack(
    const float* __restrict__ w_enc, const float* __restrict__ w_out,
    const float* __restrict__ wu, const float* __restrict__ wm,
    _Float16* __restrict__ WeP, _Float16* __restrict__ WoP,
    _Float16* __restrict__ WuP, _Float16* __restrict__ WpP) {
  int gid = blockIdx.x * 256 + threadIdx.x;  // grid exact: 118*256 = 30208 = 472*64
  int fid = gid >> 6, lane = gid & 63;
  int mrow = lane & 15, quad = lane >> 4;
  const float* src; _Float16* dst; int stride, NI, f, g;
  if (fid < 32) {
    f = fid; g = f; src = w_enc; dst = WeP; stride = 128; NI = 8;
  } else if (fid < 72) {
    f = fid - 32; g = f; src = w_out; dst = WoP; stride = 160; NI = 8;
  } else if (fid < 272) {
    f = fid - 72; g = f % 100; src = wu + (f / 100) * 51200; dst = WuP; stride = 320; NI = 10;
  } else {
    f = fid - 272; g = f % 50;
    int l = f / 100, h = (f % 100) / 50;
    src = wm + l * 51200 + h * 160; dst = WpP; stride = 320; NI = 10;
  }
  int kk = g / NI, i = g - kk * NI;
  const float* sp = src + (size_t)(i * 16 + mrow) * stride + kk * 32 + quad * 8;
  float4 f0 = *(const float4*)sp;
  float4 f1 = *(const float4*)(sp + 4);
  half8 v = {(_Float16)f0.x, (_Float16)f0.y, (_Float16)f0.z, (_Float16)f0.w,
             (_Float16)f1.x, (_Float16)f1.y, (_Float16)f1.z, (_Float16)f1.w};
  *(half8*)&dst[(size_t)(f * 64 + lane) * 8] = v;
}

// ---------------------------------------------------------------- CSR build
__global__ __launch_bounds__(256) void k_count_i(const int* __restrict__ ei,
                                                 int* __restrict__ cnti) {
  int e = blockIdx.x * 256 + threadIdx.x;  // grid exact: 3125*256 = 800000
  atomicAdd(&cnti[ei[NE + e]], 1);
}

__global__ __launch_bounds__(256) void k_scan1(const int* __restrict__ cnti,
                                               int* __restrict__ off,
                                               int* __restrict__ bsum) {
  __shared__ int sh[256];
  const int t = threadIdx.x;
  const int i = blockIdx.x * 256 + t;  // grid 391 covers 100096
  int v = (i < NN) ? cnti[i] : 0;
  sh[t] = v;
  __syncthreads();
  for (int d = 1; d < 256; d <<= 1) {
    int add = (t >= d) ? sh[t - d] : 0;
    __syncthreads();
    sh[t] += add;
    __syncthreads();
  }
  if (i < NN) off[i] = sh[t] - v;
  if (t == 255) bsum[blockIdx.x] = sh[255];
}

__global__ __launch_bounds__(512) void k_scan2(const int* __restrict__ bsum,
                                               int* __restrict__ bsum2) {
  __shared__ int sh[512];
  const int t = threadIdx.x;
  int v = (t < 391) ? bsum[t] : 0;
  sh[t] = v;
  __syncthreads();
  for (int d = 1; d < 512; d <<= 1) {
    int add = (t >= d) ? sh[t - d] : 0;
    __syncthreads();
    sh[t] += add;
    __syncthreads();
  }
  if (t < 391) bsum2[t] = sh[t] - v;
}

__global__ __launch_bounds__(256) void k_scan3(int* __restrict__ off,
                                               const int* __restrict__ bsum2,
                                               int* __restrict__ cursor) {
  const int i = blockIdx.x * 256 + threadIdx.x;
  if (i < NN) {
    int o = off[i] + bsum2[blockIdx.x];
    off[i] = o;
    cursor[i] = o;
  }
  if (i == 0) off[NN] = NE;
}

__global__ __launch_bounds__(256) void k_scatter(const int* __restrict__ ei,
                                                 const float* __restrict__ ew,
                                                 int* __restrict__ cursor,
                                                 int2* __restrict__ selist) {
  int e = blockIdx.x * 256 + threadIdx.x;  // grid exact 3125
  int dst = ei[NE + e];
  int pos = atomicAdd(&cursor[dst], 1);
  selist[pos] = make_int2(ei[e], __float_as_int(ew[e]));
}

// ---------------------------------------------------------------- helpers
__device__ __forceinline__ half8 cvt8(const float* p) {
  float4 f0 = *(const float4*)p;
  float4 f1 = *(const float4*)(p + 4);
  half8 a = {(_Float16)f0.x, (_Float16)f0.y, (_Float16)f0.z, (_Float16)f0.w,
             (_Float16)f1.x, (_Float16)f1.y, (_Float16)f1.z, (_Float16)f1.w};
  return a;
}

// group loads: fragments are linear (frag = g*W + ii for group width W)
__device__ __forceinline__ void ldg5(half8 d[5], const _Float16* Wf, int g) {
#pragma unroll
  for (int ii = 0; ii < 5; ++ii) d[ii] = LDB(Wf, g * 5 + ii);
}
__device__ __forceinline__ void ldg4(half8 d[4], const _Float16* Wf, int g) {
#pragma unroll
  for (int ii = 0; ii < 4; ++ii) d[ii] = LDB(Wf, g * 4 + ii);
}

// wave-local vectorized h16 writer: 16 rows x 20 pieces = 320 chunks over 64 lanes
__device__ __forceinline__ void write_h16_wave(_Float16* __restrict__ h16,
                                               const _Float16* tile, int n0,
                                               int lane) {
#pragma unroll
  for (int u = 0; u < 5; ++u) {
    int c = lane + u * 64;
    int row = c / 20, col = (c - row * 20) * 8;
    *(half8*)&h16[(size_t)(n0 + row) * 160 + col] = *(const half8*)&tile[row * 168 + col];
  }
}

// ---------------------------------------------------------------- shared phase 2: P = tile @ Wp^T
// 1 wave, 16 rows; double-buffered 5-frag groups with cross-half prefetch.
// Also emits per-node LN moments S12[n] = {S1src, S2src, S1dst, S2dst} (f16-rounded).
// Precondition: bA holds half0 group0.
__device__ __forceinline__ void phase2_proj(
    const _Float16* __restrict__ WpP, const float* __restrict__ bm,
    _Float16* __restrict__ P, float* __restrict__ S12,
    const _Float16* tile, half8 bA[5], half8 bB[5],
    int lane, int mrow, int quad, int n0) {
#pragma unroll
  for (int half_ = 0; half_ < 2; ++half_) {
    const _Float16* Wf = WpP + half_ * 25600 + lane * 8;
    const _Float16* Wfn = WpP + 25600 + lane * 8;
    floatx4 acc2[10];
#pragma unroll
    for (int i = 0; i < 10; ++i) acc2[i] = (floatx4)0.f;
    half8 a_cur = *(const half8*)&tile[mrow * 168 + quad * 8];
#pragma unroll
    for (int g = 0; g < 10; ++g) {
      half8* bc = (g & 1) ? bB : bA;
      half8* bn = (g & 1) ? bA : bB;
      if (g + 1 < 10) ldg5(bn, Wf, g + 1);
      else if (half_ == 0) ldg5(bn, Wfn, 0);  // prefetch next half's group0
      half8 a_use = a_cur;
      if ((g & 1) && g < 9) {
        int kk1 = (g + 1) >> 1;
        a_cur = *(const half8*)&tile[mrow * 168 + kk1 * 32 + quad * 8];
      }
      const int ib = (g & 1) * 5;
#pragma unroll
      for (int ii = 0; ii < 5; ++ii)
        acc2[ib + ii] = __builtin_amdgcn_mfma_f32_16x16x32_f16(a_use, bc[ii], acc2[ib + ii], 0, 0, 0);
    }
#pragma unroll
    for (int r = 0; r < 4; ++r) {
      const int row = quad * 4 + r;
      _Float16* prow = &P[(size_t)(n0 + row) * 320 + half_ * 160];
      float s1 = 0.f, s2 = 0.f;
#pragma unroll
      for (int i = 0; i < 10; ++i) {
        int jj = i * 16 + mrow;
        _Float16 hv = (_Float16)(acc2[i][r] + (half_ ? bm[jj] : 0.f));
        prow[jj] = hv;
        float fv = (float)hv;
        s1 += fv; s2 = fmaf(fv, fv, s2);
      }
      // reduce over the 16 mrow lanes (offsets 1..8 stay within the quad)
#pragma unroll
      for (int off = 1; off < 16; off <<= 1) { s1 += __shfl_xor(s1, off); s2 += __shfl_xor(s2, off); }
      if (mrow == 0)
        *(float2*)&S12[(size_t)(n0 + row) * 4 + half_ * 2] = make_float2(s1, s2);
    }
  }
}

// ---------------------------------------------------------------- fused encoder + proj (64 thr, 16 nodes)
__global__ __launch_bounds__(64, 4) void k_encode_proj(
    const float* __restrict__ x, const float* __restrict__ tsp,
    const _Float16* __restrict__ WeP,
    const float* __restrict__ b_enc, const float* __restrict__ g_enc,
    const float* __restrict__ be_enc,
    const float* __restrict__ w_time, const float* __restrict__ b_time,
    const float* __restrict__ g_time, const float* __restrict__ be_time,
    const _Float16* __restrict__ WpP, const float* __restrict__ bm,
    _Float16* __restrict__ h16, _Float16* __restrict__ P,
    float* __restrict__ S12) {
  __shared__ _Float16 tile[16 * 168];
  const int lane = threadIdx.x;
  const int mrow = lane & 15, quad = lane >> 4;
  const int n0 = blockIdx.x * 16;  // grid 6250 exact
  const float* xrow = x + (size_t)(n0 + mrow) * 128;
  const _Float16* Wf = WeP + lane * 8;
  half8 cA[4], cB[4];
  ldg4(cA, Wf, 0);
  // time-LN closed-form constants (hides group-0 latency)
  float mw = 0.f, mb = 0.f;
  for (int d = 0; d < 32; ++d) { mw += w_time[d]; mb += b_time[d]; }
  mw *= (1.f / 32.f); mb *= (1.f / 32.f);
  float A = 0.f, B = 0.f, C = 0.f;
  for (int d = 0; d < 32; ++d) {
    float a = w_time[d] - mw, c = b_time[d] - mb;
    A = fmaf(a, a, A); B = fmaf(a, c, B); C = fmaf(c, c, C);
  }
  A *= (1.f / 32.f); B *= (1.f / 32.f); C *= (1.f / 32.f);
  // phase 1: h = x @ We^T — 8 groups of 4, double-buffered
  floatx4 acc[8];
#pragma unroll
  for (int i = 0; i < 8; ++i) acc[i] = (floatx4)0.f;
  half8 a_cur = cvt8(&xrow[quad * 8]);
#pragma unroll
  for (int g = 0; g < 8; ++g) {
    half8* bc = (g & 1) ? cB : cA;
    half8* bn = (g & 1) ? cA : cB;
    if (g + 1 < 8) ldg4(bn, Wf, g + 1);
    half8 a_use = a_cur;
    if ((g & 1) && g < 7) {
      int kk1 = (g + 1) >> 1;
      a_cur = cvt8(&xrow[kk1 * 32 + quad * 8]);
    }
    const int ib = (g & 1) * 4;
#pragma unroll
    for (int ii = 0; ii < 4; ++ii)
      acc[ib + ii] = __builtin_amdgcn_mfma_f32_16x16x32_f16(a_use, bc[ii], acc[ib + ii], 0, 0, 0);
  }
  // prefetch phase-2 half0 group0 (hides under epilogue VALU)
  half8 bA[5], bB[5];
  ldg5(bA, WpP + lane * 8, 0);
  // epilogue: LN(128) + relu -> tile
#pragma unroll
  for (int r = 0; r < 4; ++r) {
    const int row = quad * 4 + r;
    float v[8], s = 0.f, ss = 0.f;
#pragma unroll
    for (int i = 0; i < 8; ++i) {
      v[i] = acc[i][r] + b_enc[i * 16 + mrow];
      s += v[i]; ss = fmaf(v[i], v[i], ss);
    }
#pragma unroll
    for (int off = 1; off < 16; off <<= 1) { s += __shfl_xor(s, off); ss += __shfl_xor(ss, off); }
    const float m = s * (1.f / 128.f);
    const float rs = rsqrtf(ss * (1.f / 128.f) - m * m + 1e-5f);
#pragma unroll
    for (int i = 0; i < 8; ++i) {
      int j = i * 16 + mrow;
      tile[row * 168 + j] =
          (_Float16)fmaxf(fmaf((v[i] - m) * rs, g_enc[j], be_enc[j]), 0.f);
    }
  }
  // time dims 128..159 (closed-form LN): 16 nodes x 32 dims = 512
#pragma unroll
  for (int rr = 0; rr < 8; ++rr) {
    int q = lane + rr * 64;
    int nn = q >> 5, d = q & 31;
    float tsv = tsp[n0 + nn];
    float mt = fmaf(mw, tsv, mb);
    float rst = rsqrtf(fmaf(fmaf(A, tsv, 2.f * B), tsv, C) + 1e-5f);
    float vv = fmaf(w_time[d], tsv, b_time[d]);
    float y = fmaxf(fmaf((vv - mt) * rst, g_time[d], be_time[d]), 0.f);
    tile[nn * 168 + 128 + d] = (_Float16)y;
  }
  // wave-local tile handoff (no barrier)
  write_h16_wave(h16, tile, n0, lane);
  phase2_proj(WpP, bm, P, S12, tile, bA, bB, lane, mrow, quad, n0);
}

// ---------------------------------------------------------------- edge aggregate v4
// 1 node per wave; lanes 0-31 process edge k, lanes 32-63 edge k+1 (no intra-wave
// divergence: single e0/e1 per wave). LN moments via precomputed S12:
// sum(v) = S1src+S1dst; sum(v^2) = S2src+S2dst+2*dot(ps,pd) — only dot is reduced.
__global__ __launch_bounds__(256) void k_edge4(
    const _Float16* __restrict__ P, const int* __restrict__ off,
    const int2* __restrict__ selist, const float* __restrict__ S12,
    const float* __restrict__ gm, const float* __restrict__ bem,
    _Float16* __restrict__ msum16) {
  const int t = threadIdx.x;
  const int lane = t & 63;
  const int h = lane >> 5, jg = lane & 31;
  const int n = blockIdx.x * 4 + (t >> 6);  // grid exact: 25000*4 = 100000
  float gmv[5], bev[5], pdv[5];
#pragma unroll
  for (int i = 0; i < 4; ++i) { gmv[i] = gm[4 * jg + i]; bev[i] = bem[4 * jg + i]; }
  gmv[4] = gm[128 + jg]; bev[4] = bem[128 + jg];
  const _Float16* pd = P + (size_t)n * 320 + 160;
  half4 pdh = *(const half4*)&pd[4 * jg];
  pdv[0] = (float)pdh.x; pdv[1] = (float)pdh.y; pdv[2] = (float)pdh.z; pdv[3] = (float)pdh.w;
  pdv[4] = (float)pd[128 + jg];
  const float2 sdst = *(const float2*)&S12[(size_t)n * 4 + 2];
  float acc[5] = {0.f, 0.f, 0.f, 0.f, 0.f};
  const int e0 = off[n], e1 = off[n + 1];
  for (int k = e0; k < e1; k += 2) {
    int e = k + h;
    const bool val = e < e1;
    if (!val) e = e1 - 1;
    const int2 se = selist[e];
    const float we = val ? __int_as_float(se.y) : 0.f;
    const _Float16* ps = P + (size_t)se.x * 320;
    half4 a4 = *(const half4*)&ps[4 * jg];
    float a5 = (float)ps[128 + jg];
    const float2 ssrc = *(const float2*)&S12[(size_t)se.x * 4];
    float v[5];
    v[0] = (float)a4.x + pdv[0]; v[1] = (float)a4.y + pdv[1];
    v[2] = (float)a4.z + pdv[2]; v[3] = (float)a4.w + pdv[3];
    v[4] = a5 + pdv[4];
    float dot = 0.f;
    dot = fmaf((float)a4.x, pdv[0], dot); dot = fmaf((float)a4.y, pdv[1], dot);
    dot = fmaf((float)a4.z, pdv[2], dot); dot = fmaf((float)a4.w, pdv[3], dot);
    dot = fmaf(a5, pdv[4], dot);
#pragma unroll
    for (int o = 1; o < 32; o <<= 1) dot += __shfl_xor(dot, o);  // within 32-lane half
    const float m = (ssrc.x + sdst.x) * (1.f / 160.f);
    const float rs = rsqrtf(fmaf(2.f, dot, ssrc.y + sdst.y) * (1.f / 160.f) - m * m + 1e-5f);
#pragma unroll
    for (int i = 0; i < 5; ++i)
      acc[i] = fmaf(fmaxf(fmaf((v[i] - m) * rs, gmv[i], bev[i]), 0.f), we, acc[i]);
  }
  // combine even/odd halves
#pragma unroll
  for (int i = 0; i < 5; ++i) acc[i] += __shfl_xor(acc[i], 32);
  const float c = (float)(e1 - e0);
  const float ic = (c > 0.f) ? 1.f / (c + 1e-8f) : 0.f;
  if (h == 0) {
    _Float16* orow = msum16 + (size_t)n * 160;
    half4 o4 = {(_Float16)(acc[0] * ic), (_Float16)(acc[1] * ic),
                (_Float16)(acc[2] * ic), (_Float16)(acc[3] * ic)};
    *(half4*)&orow[4 * jg] = o4;
    orow[128 + jg] = (_Float16)(acc[4] * ic);
  }
}

// ---------------------------------------------------------------- shared update phase 1 -> tile (1 wave, 16 rows)
// Double-buffered 5-frag groups; on exit bA holds phase-2 half0 group0.
__device__ __forceinline__ void update_phase1(
    const _Float16* __restrict__ h16, const _Float16* __restrict__ msum16,
    const _Float16* __restrict__ WuP, const float* __restrict__ bu,
    const float* __restrict__ gu, const float* __restrict__ beu,
    const float* __restrict__ wg, const float* __restrict__ bg,
    const _Float16* __restrict__ WpPf,  // phase-2 prefetch base (+lane*8 applied by caller)
    _Float16* tile, half8 bA[5], half8 bB[5],
    int lane, int mrow, int quad, int n0) {
  const _Float16* h0 = h16 + (size_t)(n0 + mrow) * 160;
  const _Float16* ms0 = msum16 + (size_t)(n0 + mrow) * 160;
  const _Float16* Wf = WuP + lane * 8;
  ldg5(bA, Wf, 0);
  // gate dot (transient h loads; hides group-0 latency)
  float gp = 0.f;
#pragma unroll
  for (int kt = 0; kt < 5; ++kt) {
    half8 ha = *(const half8*)&h0[kt * 32 + quad * 8];
    float4 g0 = *(const float4*)&wg[kt * 32 + quad * 8];
    float4 g1 = *(const float4*)&wg[kt * 32 + quad * 8 + 4];
    gp = fmaf((float)ha[0], g0.x, gp); gp = fmaf((float)ha[1], g0.y, gp);
    gp = fmaf((float)ha[2], g0.z, gp); gp = fmaf((float)ha[3], g0.w, gp);
    gp = fmaf((float)ha[4], g1.x, gp); gp = fmaf((float)ha[5], g1.y, gp);
    gp = fmaf((float)ha[6], g1.z, gp); gp = fmaf((float)ha[7], g1.w, gp);
  }
  gp += __shfl_xor(gp, 16); gp += __shfl_xor(gp, 32);
  const float twv = 1.f / (1.f + expf(-(gp + bg[0])));
  // K=320: 20 groups of 5, double-buffered, zero barriers
  floatx4 acc[10];
#pragma unroll
  for (int i = 0; i < 10; ++i) acc[i] = (floatx4)0.f;
  half8 a_cur = *(const half8*)&h0[quad * 8];
#pragma unroll
  for (int g = 0; g < 20; ++g) {
    half8* bc = (g & 1) ? bB : bA;
    half8* bn = (g & 1) ? bA : bB;
    if (g + 1 < 20) ldg5(bn, Wf, g + 1);
    half8 a_use = a_cur;
    if ((g & 1) && g < 19) {
      int kk1 = (g + 1) >> 1;
      const _Float16* ap = (kk1 < 5) ? h0 + kk1 * 32 : ms0 + (kk1 - 5) * 32;
      a_cur = *(const half8*)&ap[quad * 8];
    }
    const int ib = (g & 1) * 5;
#pragma unroll
    for (int ii = 0; ii < 5; ++ii)
      acc[ib + ii] = __builtin_amdgcn_mfma_f32_16x16x32_f16(a_use, bc[ii], acc[ib + ii], 0, 0, 0);
  }
  // prefetch phase-2 group0 into bA (last bA read was g=18; hides under epilogue)
  ldg5(bA, WpPf, 0);
  // epilogue: LN + relu + gate blend -> tile
#pragma unroll
  for (int r = 0; r < 4; ++r) {
    const int row = quad * 4 + r;
    float v[10], s = 0.f, ss = 0.f;
#pragma unroll
    for (int i = 0; i < 10; ++i) {
      v[i] = acc[i][r] + bu[i * 16 + mrow];
      s += v[i]; ss = fmaf(v[i], v[i], ss);
    }
#pragma unroll
    for (int off = 1; off < 16; off <<= 1) { s += __shfl_xor(s, off); ss += __shfl_xor(ss, off); }
    const float m = s * (1.f / 160.f);
    const float rs = rsqrtf(ss * (1.f / 160.f) - m * m + 1e-5f);
    const float g = __shfl(twv, row);
    const _Float16* hr = h16 + (size_t)(n0 + row) * 160;
#pragma unroll
    for (int i = 0; i < 10; ++i) {
      int j = i * 16 + mrow;
      float hnew = fmaxf(fmaf((v[i] - m) * rs, gu[j], beu[j]), 0.f);
      float hold = (float)hr[j];
      tile[row * 168 + j] = (_Float16)fmaf(g, hnew - hold, hold);
    }
  }
}

// ---------------------------------------------------------------- fused update + proj (64 thr, 16 nodes)
__global__ __launch_bounds__(64, 4) void k_update_proj(
    _Float16* __restrict__ h16, const _Float16* __restrict__ msum16,
    const _Float16* __restrict__ WuP, const float* __restrict__ bu,
    const float* __restrict__ gu, const float* __restrict__ beu,
    const float* __restrict__ wg, const float* __restrict__ bg,
    const _Float16* __restrict__ WpP, const float* __restrict__ bm,
    _Float16* __restrict__ P, float* __restrict__ S12) {
  __shared__ _Float16 tile[16 * 168];
  const int lane = threadIdx.x;
  const int mrow = lane & 15, quad = lane >> 4;
  const int n0 = blockIdx.x * 16;  // grid 6250 exact
  half8 bA[5], bB[5];
  update_phase1(h16, msum16, WuP, bu, gu, beu, wg, bg,
                WpP + lane * 8, tile, bA, bB, lane, mrow, quad, n0);
  write_h16_wave(h16, tile, n0, lane);
  phase2_proj(WpP, bm, P, S12, tile, bA, bB, lane, mrow, quad, n0);
}

// ---------------------------------------------------------------- fused update + output proj + L2 norm
__global__ __launch_bounds__(64, 4) void k_update_out(
    const _Float16* __restrict__ h16, const _Float16* __restrict__ msum16,
    const _Float16* __restrict__ WuP, const float* __restrict__ bu,
    const float* __restrict__ gu, const float* __restrict__ beu,
    const float* __restrict__ wg, const float* __restrict__ bg,
    const _Float16* __restrict__ WoP, const float* __restrict__ b_out,
    float* __restrict__ out) {
  __shared__ _Float16 tile[16 * 168];
  const int lane = threadIdx.x;
  const int mrow = lane & 15, quad = lane >> 4;
  const int n0 = blockIdx.x * 16;  // grid 6250 exact
  half8 bA[5], bB[5];
  // phase-2 here uses Wo groups of 4; reuse bA[0..3] slot via dedicated buffers below.
  update_phase1(h16, msum16, WuP, bu, gu, beu, wg, bg,
                WoP + lane * 8, tile, bA, bB, lane, mrow, quad, n0);
  // NOTE: update_phase1 prefetched ldg5(bA, WoP..., 0) = Wo frags 0..4; phase-2 groups
  // are width-4, so do NOT use the prefetch directly — copy overlap: frags 0..3 = group 0.
  const _Float16* Wf2 = WoP + lane * 8;
  half8 cA[4], cB[4];
#pragma unroll
  for (int ii = 0; ii < 4; ++ii) cA[ii] = bA[ii];  // group 0 already in regs
  // phase 2: out = L2norm(tile @ Wo^T + b_out); 10 groups of 4, double-buffered
  floatx4 acc2[8];
#pragma unroll
  for (int i = 0; i < 8; ++i) acc2[i] = (floatx4)0.f;
  half8 a_cur = *(const half8*)&tile[mrow * 168 + quad * 8];
#pragma unroll
  for (int g = 0; g < 10; ++g) {
    half8* bc = (g & 1) ? cB : cA;
    half8* bn = (g & 1) ? cA : cB;
    if (g + 1 < 10) ldg4(bn, Wf2, g + 1);
    half8 a_use = a_cur;
    if ((g & 1) && g < 9) {
      int kk1 = (g + 1) >> 1;
      a_cur = *(const half8*)&tile[mrow * 168 + kk1 * 32 + quad * 8];
    }
    const int ib = (g & 1) * 4;
#pragma unroll
    for (int ii = 0; ii < 4; ++ii)
      acc2[ib + ii] = __builtin_amdgcn_mfma_f32_16x16x32_f16(a_use, bc[ii], acc2[ib + ii], 0, 0, 0);
  }
#pragma unroll
  for (int r = 0; r < 4; ++r) {
    const int row = quad * 4 + r;
    float v[8], ss = 0.f;
#pragma unroll
    for (int i = 0; i < 8; ++i) {
      v[i] = acc2[i][r] + b_out[i * 16 + mrow];
      ss = fmaf(v[i], v[i], ss);
    }
#pragma unroll
    for (int off = 1; off < 16; off <<= 1) ss += __shfl_xor(ss, off);
    const float inv = 1.f / fmaxf(sqrtf(ss), 1e-12f);
#pragma unroll
    for (int i = 0; i < 8; ++i)
      out[(size_t)(n0 + row) * 128 + i * 16 + mrow] = v[i] * inv;
  }
}

// ---------------------------------------------------------------- launch
extern "C" void kernel_launch(void* const* d_in, const int* in_sizes, int n_in,
                              void* d_out, int out_size, void* d_ws, size_t ws_size,
                              hipStream_t stream) {
  (void)in_sizes; (void)n_in; (void)out_size; (void)ws_size;
  const float* x       = (const float*)d_in[0];
  const int*   ei      = (const int*)  d_in[1];
  const float* ew      = (const float*)d_in[2];
  const float* tsp     = (const float*)d_in[3];
  const float* w_enc   = (const float*)d_in[4];
  const float* b_enc   = (const float*)d_in[5];
  const float* g_enc   = (const float*)d_in[6];
  const float* be_enc  = (const float*)d_in[7];
  const float* w_time  = (const float*)d_in[8];
  const float* b_time  = (const float*)d_in[9];
  const float* g_time  = (const float*)d_in[10];
  const float* be_time = (const float*)d_in[11];
  const float* wm      = (const float*)d_in[12];
  const float* bm      = (const float*)d_in[13];
  const float* gm      = (const float*)d_in[14];
  const float* bem     = (const float*)d_in[15];
  const float* wu      = (const float*)d_in[16];
  const float* bu      = (const float*)d_in[17];
  const float* gu      = (const float*)d_in[18];
  const float* beu     = (const float*)d_in[19];
  const float* wg      = (const float*)d_in[20];
  const float* bg      = (const float*)d_in[21];
  const float* w_out   = (const float*)d_in[22];
  const float* b_out   = (const float*)d_in[23];
  float* out = (float*)d_out;

  // ws layout (bytes): h16 f16[NN*160] @0 (32M) | msum16 f16[NN*160] @32,000,000 (32M)
  //   P f16[NN*320] @64,000,000 (64M) | WuP @128,000,000 (204,800) | WoP @128,204,800 (40,960)
  char* ws = (char*)d_ws;
  _Float16* h16    = (_Float16*)ws;
  _Float16* msum16 = (_Float16*)(ws + 32000000);
  _Float16* P      = (_Float16*)(ws + 64000000);
  _Float16* WuP16  = (_Float16*)(ws + 128000000);
  _Float16* WoP16  = (_Float16*)(ws + 128204800);
  // d_out doubles as scratch; k_update_out reads only ws-resident scratch and
  // overwrites everything below AFTER the last S12/selist read (stream-ordered).
  char* ob = (char*)d_out;
  _Float16* WpP16 = (_Float16*)ob;            // 204,800
  _Float16* WeP16 = (_Float16*)(ob + 204800); // 32,768
  int* off    = (int*)(ob + 237568);          // 400,016
  int* cnti   = (int*)(ob + 637584);          // 400,000
  int* cursor = (int*)(ob + 1037584);         // 400,000
  int* bsum   = (int*)(ob + 1437584);         // 1,568
  int* bsum2  = (int*)(ob + 1439152);         // 1,568
  int2* selist = (int2*)(ob + 1440720);       // 6,400,000 -> 7,840,720
  float* S12  = (float*)(ob + 7840720);       // 1,600,000 -> 9,440,720 < 51,200,000

  // weight prep + CSR build (edges static across layers: build once)
  k_zero<<<dim3(98), dim3(256), 0, stream>>>((float4*)cnti, 25000);
  k_pack<<<dim3(118), dim3(256), 0, stream>>>(w_enc, w_out, wu, wm,
                                              WeP16, WoP16, WuP16, WpP16);
  k_count_i<<<dim3(3125), dim3(256), 0, stream>>>(ei, cnti);
  k_scan1<<<dim3(391), dim3(256), 0, stream>>>(cnti, off, bsum);
  k_scan2<<<dim3(1), dim3(512), 0, stream>>>(bsum, bsum2);
  k_scan3<<<dim3(391), dim3(256), 0, stream>>>(off, bsum2, cursor);
  k_scatter<<<dim3(3125), dim3(256), 0, stream>>>(ei, ew, cursor, selist);

  k_encode_proj<<<dim3(6250), dim3(64), 0, stream>>>(
      x, tsp, WeP16, b_enc, g_enc, be_enc, w_time, b_time, g_time, be_time,
      WpP16, bm, h16, P, S12);
  k_edge4<<<dim3(25000), dim3(256), 0, stream>>>(P, off, selist, S12, gm, bem, msum16);
  k_update_proj<<<dim3(6250), dim3(64), 0, stream>>>(
      h16, msum16, WuP16, bu, gu, beu, wg, bg,
      WpP16 + 51200, bm + 160, P, S12);
  k_edge4<<<dim3(25000), dim3(256), 0, stream>>>(P, off, selist, S12, gm + 160, bem + 160, msum16);
  k_update_out<<<dim3(6250), dim3(64), 0, stream>>>(
      h16, msum16, WuP16 + 51200, bu + 160, gu + 160, beu + 160, wg + 160, bg + 1,
      WoP16, b_out, out);
}

// Round 9
// 539.654 us; speedup vs baseline: 1.0790x; 1.0790x over previous
//
#include <hip/hip_runtime.h>

#define NN 100000
#define NE 800000
// D = 160, 2D = 320, F = 128

typedef _Float16 half8 __attribute__((ext_vector_type(8)));
typedef _Float16 half4 __attribute__((ext_vector_type(4)));
typedef _Float16 half2v __attribute__((ext_vector_type(2)));
typedef float floatx4 __attribute__((ext_vector_type(4)));

#define LDB(Wf, f) (*(const half8*)&(Wf)[(f) * 512])

// ---------------------------------------------------------------- zero
__global__ __launch_bounds__(256) void k_zero(float4* __restrict__ p, int n4) {
  int i = blockIdx.x * 256 + threadIdx.x;
  if (i < n4) p[i] = make_float4(0.f, 0.f, 0.f, 0.f);
}

// ---------------------------------------------------------------- fragment-pack all weights
// Fragment f=(kk,i): 1KB chunk, lane reads 16B at dst[f*1024 + lane*16].
// b for lane(mrow,quad) of frag (kk,i) = W[i*16+mrow][kk*32+quad*8 .. +8].
// Segments: We 32 frags | Wo 40 | Wu 2x100 | Wp 2x2x50.  472 frags x 64 lanes.
__global__ __launch_bounds__(256) void k_pack(
    const float* __restrict__ w_enc, const float* __restrict__ w_out,
    const float* __restrict__ wu, const float* __restrict__ wm,
    _Float16* __restrict__ WeP, _Float16* __restrict__ WoP,
    _Float16* __restrict__ WuP, _Float16* __restrict__ WpP) {
  int gid = blockIdx.x * 256 + threadIdx.x;  // grid exact: 118*256 = 30208 = 472*64
  int fid = gid >> 6, lane = gid & 63;
  int mrow = lane & 15, quad = lane >> 4;
  const float* src; _Float16* dst; int stride, NI, f, g;
  if (fid < 32) {
    f = fid; g = f; src = w_enc; dst = WeP; stride = 128; NI = 8;
  } else if (fid < 72) {
    f = fid - 32; g = f; src = w_out; dst = WoP; stride = 160; NI = 8;
  } else if (fid < 272) {
    f = fid - 72; g = f % 100; src = wu + (f / 100) * 51200; dst = WuP; stride = 320; NI = 10;
  } else {
    f = fid - 272; g = f % 50;
    int l = f / 100, h = (f % 100) / 50;
    src = wm + l * 51200 + h * 160; dst = WpP; stride = 320; NI = 10;
  }
  int kk = g / NI, i = g - kk * NI;
  const float* sp = src + (size_t)(i * 16 + mrow) * stride + kk * 32 + quad * 8;
  float4 f0 = *(const float4*)sp;
  float4 f1 = *(const float4*)(sp + 4);
  half8 v = {(_Float16)f0.x, (_Float16)f0.y, (_Float16)f0.z, (_Float16)f0.w,
             (_Float16)f1.x, (_Float16)f1.y, (_Float16)f1.z, (_Float16)f1.w};
  *(half8*)&dst[(size_t)(f * 64 + lane) * 8] = v;
}

// ---------------------------------------------------------------- CSR build
__global__ __launch_bounds__(256) void k_count_i(const int* __restrict__ ei,
                                                 int* __restrict__ cnti) {
  int e = blockIdx.x * 256 + threadIdx.x;  // grid exact: 3125*256 = 800000
  atomicAdd(&cnti[ei[NE + e]], 1);
}

__global__ __launch_bounds__(256) void k_scan1(const int* __restrict__ cnti,
                                               int* __restrict__ off,
                                               int* __restrict__ bsum) {
  __shared__ int sh[256];
  const int t = threadIdx.x;
  const int i = blockIdx.x * 256 + t;  // grid 391 covers 100096
  int v = (i < NN) ? cnti[i] : 0;
  sh[t] = v;
  __syncthreads();
  for (int d = 1; d < 256; d <<= 1) {
    int add = (t >= d) ? sh[t - d] : 0;
    __syncthreads();
    sh[t] += add;
    __syncthreads();
  }
  if (i < NN) off[i] = sh[t] - v;
  if (t == 255) bsum[blockIdx.x] = sh[255];
}

__global__ __launch_bounds__(512) void k_scan2(const int* __restrict__ bsum,
                                               int* __restrict__ bsum2) {
  __shared__ int sh[512];
  const int t = threadIdx.x;
  int v = (t < 391) ? bsum[t] : 0;
  sh[t] = v;
  __syncthreads();
  for (int d = 1; d < 512; d <<= 1) {
    int add = (t >= d) ? sh[t - d] : 0;
    __syncthreads();
    sh[t] += add;
    __syncthreads();
  }
  if (t < 391) bsum2[t] = sh[t] - v;
}

__global__ __launch_bounds__(256) void k_scan3(int* __restrict__ off,
                                               const int* __restrict__ bsum2,
                                               int* __restrict__ cursor) {
  const int i = blockIdx.x * 256 + threadIdx.x;
  if (i < NN) {
    int o = off[i] + bsum2[blockIdx.x];
    off[i] = o;
    cursor[i] = o;
  }
  if (i == 0) off[NN] = NE;
}

__global__ __launch_bounds__(256) void k_scatter(const int* __restrict__ ei,
                                                 const float* __restrict__ ew,
                                                 int* __restrict__ cursor,
                                                 int2* __restrict__ selist) {
  int e = blockIdx.x * 256 + threadIdx.x;  // grid exact 3125
  int dst = ei[NE + e];
  int pos = atomicAdd(&cursor[dst], 1);
  selist[pos] = make_int2(ei[e], __float_as_int(ew[e]));
}

// ---------------------------------------------------------------- helpers
__device__ __forceinline__ half8 cvt8(const float* p) {
  float4 f0 = *(const float4*)p;
  float4 f1 = *(const float4*)(p + 4);
  half8 a = {(_Float16)f0.x, (_Float16)f0.y, (_Float16)f0.z, (_Float16)f0.w,
             (_Float16)f1.x, (_Float16)f1.y, (_Float16)f1.z, (_Float16)f1.w};
  return a;
}

// group loads: fragments are linear (frag = g*W + ii for group width W)
__device__ __forceinline__ void ldg5(half8 d[5], const _Float16* Wf, int g) {
#pragma unroll
  for (int ii = 0; ii < 5; ++ii) d[ii] = LDB(Wf, g * 5 + ii);
}
__device__ __forceinline__ void ldg4(half8 d[4], const _Float16* Wf, int g) {
#pragma unroll
  for (int ii = 0; ii < 4; ++ii) d[ii] = LDB(Wf, g * 4 + ii);
}

// wave-local vectorized h16 writer: 16 rows x 20 pieces = 320 chunks over 64 lanes
__device__ __forceinline__ void write_h16_wave(_Float16* __restrict__ h16,
                                               const _Float16* tile, int n0,
                                               int lane) {
#pragma unroll
  for (int u = 0; u < 5; ++u) {
    int c = lane + u * 64;
    int row = c / 20, col = (c - row * 20) * 8;
    *(half8*)&h16[(size_t)(n0 + row) * 160 + col] = *(const half8*)&tile[row * 168 + col];
  }
}

// ---------------------------------------------------------------- shared phase 2: P = tile @ Wp^T
// 1 wave, 16 rows; double-buffered 5-frag groups with cross-half prefetch.
// Precondition: bA holds half0 group0.
__device__ __forceinline__ void phase2_proj(
    const _Float16* __restrict__ WpP, const float* __restrict__ bm,
    _Float16* __restrict__ P, const _Float16* tile, half8 bA[5], half8 bB[5],
    int lane, int mrow, int quad, int n0) {
#pragma unroll
  for (int half_ = 0; half_ < 2; ++half_) {
    const _Float16* Wf = WpP + half_ * 25600 + lane * 8;
    const _Float16* Wfn = WpP + 25600 + lane * 8;
    floatx4 acc2[10];
#pragma unroll
    for (int i = 0; i < 10; ++i) acc2[i] = (floatx4)0.f;
    half8 a_cur = *(const half8*)&tile[mrow * 168 + quad * 8];
#pragma unroll
    for (int g = 0; g < 10; ++g) {
      half8* bc = (g & 1) ? bB : bA;
      half8* bn = (g & 1) ? bA : bB;
      if (g + 1 < 10) ldg5(bn, Wf, g + 1);
      else if (half_ == 0) ldg5(bn, Wfn, 0);  // prefetch next half's group0
      half8 a_use = a_cur;
      if ((g & 1) && g < 9) {
        int kk1 = (g + 1) >> 1;
        a_cur = *(const half8*)&tile[mrow * 168 + kk1 * 32 + quad * 8];
      }
      const int ib = (g & 1) * 5;
#pragma unroll
      for (int ii = 0; ii < 5; ++ii)
        acc2[ib + ii] = __builtin_amdgcn_mfma_f32_16x16x32_f16(a_use, bc[ii], acc2[ib + ii], 0, 0, 0);
    }
#pragma unroll
    for (int r = 0; r < 4; ++r) {
      const int row = quad * 4 + r;
      _Float16* prow = &P[(size_t)(n0 + row) * 320 + half_ * 160];
#pragma unroll
      for (int i = 0; i < 10; ++i) {
        int jj = i * 16 + mrow;
        prow[jj] = (_Float16)(acc2[i][r] + (half_ ? bm[jj] : 0.f));
      }
    }
  }
}

// ---------------------------------------------------------------- fused encoder + proj (64 thr, 16 nodes)
__global__ __launch_bounds__(64, 4) void k_encode_proj(
    const float* __restrict__ x, const float* __restrict__ tsp,
    const _Float16* __restrict__ WeP,
    const float* __restrict__ b_enc, const float* __restrict__ g_enc,
    const float* __restrict__ be_enc,
    const float* __restrict__ w_time, const float* __restrict__ b_time,
    const float* __restrict__ g_time, const float* __restrict__ be_time,
    const _Float16* __restrict__ WpP, const float* __restrict__ bm,
    _Float16* __restrict__ h16, _Float16* __restrict__ P) {
  __shared__ _Float16 tile[16 * 168];
  const int lane = threadIdx.x;
  const int mrow = lane & 15, quad = lane >> 4;
  const int n0 = blockIdx.x * 16;  // grid 6250 exact
  const float* xrow = x + (size_t)(n0 + mrow) * 128;
  const _Float16* Wf = WeP + lane * 8;
  half8 cA[4], cB[4];
  ldg4(cA, Wf, 0);
  // time-LN closed-form constants (hides group-0 latency)
  float mw = 0.f, mb = 0.f;
  for (int d = 0; d < 32; ++d) { mw += w_time[d]; mb += b_time[d]; }
  mw *= (1.f / 32.f); mb *= (1.f / 32.f);
  float A = 0.f, B = 0.f, C = 0.f;
  for (int d = 0; d < 32; ++d) {
    float a = w_time[d] - mw, c = b_time[d] - mb;
    A = fmaf(a, a, A); B = fmaf(a, c, B); C = fmaf(c, c, C);
  }
  A *= (1.f / 32.f); B *= (1.f / 32.f); C *= (1.f / 32.f);
  // phase 1: h = x @ We^T — 8 groups of 4, double-buffered
  floatx4 acc[8];
#pragma unroll
  for (int i = 0; i < 8; ++i) acc[i] = (floatx4)0.f;
  half8 a_cur = cvt8(&xrow[quad * 8]);
#pragma unroll
  for (int g = 0; g < 8; ++g) {
    half8* bc = (g & 1) ? cB : cA;
    half8* bn = (g & 1) ? cA : cB;
    if (g + 1 < 8) ldg4(bn, Wf, g + 1);
    half8 a_use = a_cur;
    if ((g & 1) && g < 7) {
      int kk1 = (g + 1) >> 1;
      a_cur = cvt8(&xrow[kk1 * 32 + quad * 8]);
    }
    const int ib = (g & 1) * 4;
#pragma unroll
    for (int ii = 0; ii < 4; ++ii)
      acc[ib + ii] = __builtin_amdgcn_mfma_f32_16x16x32_f16(a_use, bc[ii], acc[ib + ii], 0, 0, 0);
  }
  // prefetch phase-2 half0 group0 (hides under epilogue VALU)
  half8 bA[5], bB[5];
  ldg5(bA, WpP + lane * 8, 0);
  // epilogue: LN(128) + relu -> tile
#pragma unroll
  for (int r = 0; r < 4; ++r) {
    const int row = quad * 4 + r;
    float v[8], s = 0.f, ss = 0.f;
#pragma unroll
    for (int i = 0; i < 8; ++i) {
      v[i] = acc[i][r] + b_enc[i * 16 + mrow];
      s += v[i]; ss = fmaf(v[i], v[i], ss);
    }
#pragma unroll
    for (int off = 1; off < 16; off <<= 1) { s += __shfl_xor(s, off); ss += __shfl_xor(ss, off); }
    const float m = s * (1.f / 128.f);
    const float rs = rsqrtf(ss * (1.f / 128.f) - m * m + 1e-5f);
#pragma unroll
    for (int i = 0; i < 8; ++i) {
      int j = i * 16 + mrow;
      tile[row * 168 + j] =
          (_Float16)fmaxf(fmaf((v[i] - m) * rs, g_enc[j], be_enc[j]), 0.f);
    }
  }
  // time dims 128..159 (closed-form LN): 16 nodes x 32 dims = 512
#pragma unroll
  for (int rr = 0; rr < 8; ++rr) {
    int q = lane + rr * 64;
    int nn = q >> 5, d = q & 31;
    float tsv = tsp[n0 + nn];
    float mt = fmaf(mw, tsv, mb);
    float rst = rsqrtf(fmaf(fmaf(A, tsv, 2.f * B), tsv, C) + 1e-5f);
    float vv = fmaf(w_time[d], tsv, b_time[d]);
    float y = fmaxf(fmaf((vv - mt) * rst, g_time[d], be_time[d]), 0.f);
    tile[nn * 168 + 128 + d] = (_Float16)y;
  }
  // wave-local tile handoff (no barrier)
  write_h16_wave(h16, tile, n0, lane);
  phase2_proj(WpP, bm, P, tile, bA, bB, lane, mrow, quad, n0);
}

// ---------------------------------------------------------------- edge aggregate v5
// 8 nodes/block; one 32-lane half per node; within a half, two 16-lane groups
// each process one edge (4 edges per wave-iteration). Lane q (0..15) owns dims
// [8q..8q+8) and [128+2q..128+2q+2) (10 dims). Reduce = 4-step butterfly over
// 16 lanes (offsets 1..8). 2-deep software pipeline on (selist, P-row) loads.
__global__ __launch_bounds__(256) void k_edge5(
    const _Float16* __restrict__ P, const int* __restrict__ off,
    const int2* __restrict__ selist,
    const float* __restrict__ gm, const float* __restrict__ bem,
    _Float16* __restrict__ msum16) {
  const int t = threadIdx.x;
  const int lane = t & 63;
  const int n = blockIdx.x * 8 + (t >> 5);  // grid exact: 12500*8 = 100000
  const int q16 = (lane >> 4) & 1;
  const int q = lane & 15;
  // stationary per-lane params
  float gmv[10], bev[10], pdv[10];
  {
    float4 g0 = *(const float4*)&gm[8 * q];
    float4 g1 = *(const float4*)&gm[8 * q + 4];
    float2 g2 = *(const float2*)&gm[128 + 2 * q];
    gmv[0] = g0.x; gmv[1] = g0.y; gmv[2] = g0.z; gmv[3] = g0.w;
    gmv[4] = g1.x; gmv[5] = g1.y; gmv[6] = g1.z; gmv[7] = g1.w;
    gmv[8] = g2.x; gmv[9] = g2.y;
    float4 b0 = *(const float4*)&bem[8 * q];
    float4 b1 = *(const float4*)&bem[8 * q + 4];
    float2 b2 = *(const float2*)&bem[128 + 2 * q];
    bev[0] = b0.x; bev[1] = b0.y; bev[2] = b0.z; bev[3] = b0.w;
    bev[4] = b1.x; bev[5] = b1.y; bev[6] = b1.z; bev[7] = b1.w;
    bev[8] = b2.x; bev[9] = b2.y;
  }
  {
    const _Float16* pd = P + (size_t)n * 320 + 160;
    half8 p8 = *(const half8*)&pd[8 * q];
    half2v p2 = *(const half2v*)&pd[128 + 2 * q];
#pragma unroll
    for (int i = 0; i < 8; ++i) pdv[i] = (float)p8[i];
    pdv[8] = (float)p2.x; pdv[9] = (float)p2.y;
  }
  float acc[10];
#pragma unroll
  for (int i = 0; i < 10; ++i) acc[i] = 0.f;
  const int e0 = off[n], e1 = off[n + 1];
  if (e0 < e1) {
    // pipeline stage regs
    float weC; half8 a8C; half2v a2C;
    {  // prologue load (k = e0)
      int e = e0 + q16;
      bool val = e < e1;
      if (!val) e = e1 - 1;
      int2 se = selist[e];
      weC = val ? __int_as_float(se.y) : 0.f;
      const _Float16* ps = P + (size_t)se.x * 320;
      a8C = *(const half8*)&ps[8 * q];
      a2C = *(const half2v*)&ps[128 + 2 * q];
    }
    for (int k = e0; k < e1; k += 2) {
      float weN = 0.f; half8 a8N = a8C; half2v a2N = a2C;
      if (k + 2 < e1) {  // prefetch next pair (uniform branch per half)
        int e = k + 2 + q16;
        bool val = e < e1;
        if (!val) e = e1 - 1;
        int2 se = selist[e];
        weN = val ? __int_as_float(se.y) : 0.f;
        const _Float16* ps = P + (size_t)se.x * 320;
        a8N = *(const half8*)&ps[8 * q];
        a2N = *(const half2v*)&ps[128 + 2 * q];
      }
      // compute current edge (per 16-lane group)
      float v[10], s = 0.f, ss = 0.f;
#pragma unroll
      for (int i = 0; i < 8; ++i) v[i] = (float)a8C[i] + pdv[i];
      v[8] = (float)a2C.x + pdv[8];
      v[9] = (float)a2C.y + pdv[9];
#pragma unroll
      for (int i = 0; i < 10; ++i) { s += v[i]; ss = fmaf(v[i], v[i], ss); }
#pragma unroll
      for (int o = 1; o < 16; o <<= 1) { s += __shfl_xor(s, o); ss += __shfl_xor(ss, o); }
      const float m = s * (1.f / 160.f);
      const float rs = rsqrtf(ss * (1.f / 160.f) - m * m + 1e-5f);
#pragma unroll
      for (int i = 0; i < 10; ++i)
        acc[i] = fmaf(fmaxf(fmaf((v[i] - m) * rs, gmv[i], bev[i]), 0.f), weC, acc[i]);
      weC = weN; a8C = a8N; a2C = a2N;
    }
  }
  // combine the two 16-lane groups of this half
#pragma unroll
  for (int i = 0; i < 10; ++i) acc[i] += __shfl_xor(acc[i], 16);
  const float c = (float)(e1 - e0);
  const float ic = (c > 0.f) ? 1.f / (c + 1e-8f) : 0.f;
  if (q16 == 0) {
    _Float16* orow = msum16 + (size_t)n * 160;
    half8 o8 = {(_Float16)(acc[0] * ic), (_Float16)(acc[1] * ic),
                (_Float16)(acc[2] * ic), (_Float16)(acc[3] * ic),
                (_Float16)(acc[4] * ic), (_Float16)(acc[5] * ic),
                (_Float16)(acc[6] * ic), (_Float16)(acc[7] * ic)};
    *(half8*)&orow[8 * q] = o8;
    half2v o2 = {(_Float16)(acc[8] * ic), (_Float16)(acc[9] * ic)};
    *(half2v*)&orow[128 + 2 * q] = o2;
  }
}

// ---------------------------------------------------------------- shared update phase 1 -> tile (1 wave, 16 rows)
// Double-buffered 5-frag groups; on exit bA holds phase-2 half0 group0.
__device__ __forceinline__ void update_phase1(
    const _Float16* __restrict__ h16, const _Float16* __restrict__ msum16,
    const _Float16* __restrict__ WuP, const float* __restrict__ bu,
    const float* __restrict__ gu, const float* __restrict__ beu,
    const float* __restrict__ wg, const float* __restrict__ bg,
    const _Float16* __restrict__ WpPf,  // phase-2 prefetch base (+lane*8 applied by caller)
    _Float16* tile, half8 bA[5], half8 bB[5],
    int lane, int mrow, int quad, int n0) {
  const _Float16* h0 = h16 + (size_t)(n0 + mrow) * 160;
  const _Float16* ms0 = msum16 + (size_t)(n0 + mrow) * 160;
  const _Float16* Wf = WuP + lane * 8;
  ldg5(bA, Wf, 0);
  // gate dot (transient h loads; hides group-0 latency)
  float gp = 0.f;
#pragma unroll
  for (int kt = 0; kt < 5; ++kt) {
    half8 ha = *(const half8*)&h0[kt * 32 + quad * 8];
    float4 g0 = *(const float4*)&wg[kt * 32 + quad * 8];
    float4 g1 = *(const float4*)&wg[kt * 32 + quad * 8 + 4];
    gp = fmaf((float)ha[0], g0.x, gp); gp = fmaf((float)ha[1], g0.y, gp);
    gp = fmaf((float)ha[2], g0.z, gp); gp = fmaf((float)ha[3], g0.w, gp);
    gp = fmaf((float)ha[4], g1.x, gp); gp = fmaf((float)ha[5], g1.y, gp);
    gp = fmaf((float)ha[6], g1.z, gp); gp = fmaf((float)ha[7], g1.w, gp);
  }
  gp += __shfl_xor(gp, 16); gp += __shfl_xor(gp, 32);
  const float twv = 1.f / (1.f + expf(-(gp + bg[0])));
  // K=320: 20 groups of 5, double-buffered, zero barriers
  floatx4 acc[10];
#pragma unroll
  for (int i = 0; i < 10; ++i) acc[i] = (floatx4)0.f;
  half8 a_cur = *(const half8*)&h0[quad * 8];
#pragma unroll
  for (int g = 0; g < 20; ++g) {
    half8* bc = (g & 1) ? bB : bA;
    half8* bn = (g & 1) ? bA : bB;
    if (g + 1 < 20) ldg5(bn, Wf, g + 1);
    half8 a_use = a_cur;
    if ((g & 1) && g < 19) {
      int kk1 = (g + 1) >> 1;
      const _Float16* ap = (kk1 < 5) ? h0 + kk1 * 32 : ms0 + (kk1 - 5) * 32;
      a_cur = *(const half8*)&ap[quad * 8];
    }
    const int ib = (g & 1) * 5;
#pragma unroll
    for (int ii = 0; ii < 5; ++ii)
      acc[ib + ii] = __builtin_amdgcn_mfma_f32_16x16x32_f16(a_use, bc[ii], acc[ib + ii], 0, 0, 0);
  }
  // prefetch phase-2 group0 into bA (last bA read was g=18; hides under epilogue)
  ldg5(bA, WpPf, 0);
  // epilogue: LN + relu + gate blend -> tile
#pragma unroll
  for (int r = 0; r < 4; ++r) {
    const int row = quad * 4 + r;
    float v[10], s = 0.f, ss = 0.f;
#pragma unroll
    for (int i = 0; i < 10; ++i) {
      v[i] = acc[i][r] + bu[i * 16 + mrow];
      s += v[i]; ss = fmaf(v[i], v[i], ss);
    }
#pragma unroll
    for (int off = 1; off < 16; off <<= 1) { s += __shfl_xor(s, off); ss += __shfl_xor(ss, off); }
    const float m = s * (1.f / 160.f);
    const float rs = rsqrtf(ss * (1.f / 160.f) - m * m + 1e-5f);
    const float g = __shfl(twv, row);
    const _Float16* hr = h16 + (size_t)(n0 + row) * 160;
#pragma unroll
    for (int i = 0; i < 10; ++i) {
      int j = i * 16 + mrow;
      float hnew = fmaxf(fmaf((v[i] - m) * rs, gu[j], beu[j]), 0.f);
      float hold = (float)hr[j];
      tile[row * 168 + j] = (_Float16)fmaf(g, hnew - hold, hold);
    }
  }
}

// ---------------------------------------------------------------- fused update + proj (64 thr, 16 nodes)
__global__ __launch_bounds__(64, 4) void k_update_proj(
    _Float16* __restrict__ h16, const _Float16* __restrict__ msum16,
    const _Float16* __restrict__ WuP, const float* __restrict__ bu,
    const float* __restrict__ gu, const float* __restrict__ beu,
    const float* __restrict__ wg, const float* __restrict__ bg,
    const _Float16* __restrict__ WpP, const float* __restrict__ bm,
    _Float16* __restrict__ P) {
  __shared__ _Float16 tile[16 * 168];
  const int lane = threadIdx.x;
  const int mrow = lane & 15, quad = lane >> 4;
  const int n0 = blockIdx.x * 16;  // grid 6250 exact
  half8 bA[5], bB[5];
  update_phase1(h16, msum16, WuP, bu, gu, beu, wg, bg,
                WpP + lane * 8, tile, bA, bB, lane, mrow, quad, n0);
  write_h16_wave(h16, tile, n0, lane);
  phase2_proj(WpP, bm, P, tile, bA, bB, lane, mrow, quad, n0);
}

// ---------------------------------------------------------------- fused update + output proj + L2 norm
__global__ __launch_bounds__(64, 4) void k_update_out(
    const _Float16* __restrict__ h16, const _Float16* __restrict__ msum16,
    const _Float16* __restrict__ WuP, const float* __restrict__ bu,
    const float* __restrict__ gu, const float* __restrict__ beu,
    const float* __restrict__ wg, const float* __restrict__ bg,
    const _Float16* __restrict__ WoP, const float* __restrict__ b_out,
    float* __restrict__ out) {
  __shared__ _Float16 tile[16 * 168];
  const int lane = threadIdx.x;
  const int mrow = lane & 15, quad = lane >> 4;
  const int n0 = blockIdx.x * 16;  // grid 6250 exact
  half8 bA[5], bB[5];
  // phase-2 here uses Wo groups of 4; reuse bA[0..3] slot via dedicated buffers below.
  update_phase1(h16, msum16, WuP, bu, gu, beu, wg, bg,
                WoP + lane * 8, tile, bA, bB, lane, mrow, quad, n0);
  // NOTE: update_phase1 prefetched ldg5(bA, WoP..., 0) = Wo frags 0..4; phase-2 groups
  // are width-4, so do NOT use the prefetch directly — copy overlap: frags 0..3 = group 0.
  const _Float16* Wf2 = WoP + lane * 8;
  half8 cA[4], cB[4];
#pragma unroll
  for (int ii = 0; ii < 4; ++ii) cA[ii] = bA[ii];  // group 0 already in regs
  // phase 2: out = L2norm(tile @ Wo^T + b_out); 10 groups of 4, double-buffered
  floatx4 acc2[8];
#pragma unroll
  for (int i = 0; i < 8; ++i) acc2[i] = (floatx4)0.f;
  half8 a_cur = *(const half8*)&tile[mrow * 168 + quad * 8];
#pragma unroll
  for (int g = 0; g < 10; ++g) {
    half8* bc = (g & 1) ? cB : cA;
    half8* bn = (g & 1) ? cA : cB;
    if (g + 1 < 10) ldg4(bn, Wf2, g + 1);
    half8 a_use = a_cur;
    if ((g & 1) && g < 9) {
      int kk1 = (g + 1) >> 1;
      a_cur = *(const half8*)&tile[mrow * 168 + kk1 * 32 + quad * 8];
    }
    const int ib = (g & 1) * 4;
#pragma unroll
    for (int ii = 0; ii < 4; ++ii)
      acc2[ib + ii] = __builtin_amdgcn_mfma_f32_16x16x32_f16(a_use, bc[ii], acc2[ib + ii], 0, 0, 0);
  }
#pragma unroll
  for (int r = 0; r < 4; ++r) {
    const int row = quad * 4 + r;
    float v[8], ss = 0.f;
#pragma unroll
    for (int i = 0; i < 8; ++i) {
      v[i] = acc2[i][r] + b_out[i * 16 + mrow];
      ss = fmaf(v[i], v[i], ss);
    }
#pragma unroll
    for (int off = 1; off < 16; off <<= 1) ss += __shfl_xor(ss, off);
    const float inv = 1.f / fmaxf(sqrtf(ss), 1e-12f);
#pragma unroll
    for (int i = 0; i < 8; ++i)
      out[(size_t)(n0 + row) * 128 + i * 16 + mrow] = v[i] * inv;
  }
}

// ---------------------------------------------------------------- launch
extern "C" void kernel_launch(void* const* d_in, const int* in_sizes, int n_in,
                              void* d_out, int out_size, void* d_ws, size_t ws_size,
                              hipStream_t stream) {
  (void)in_sizes; (void)n_in; (void)out_size; (void)ws_size;
  const float* x       = (const float*)d_in[0];
  const int*   ei      = (const int*)  d_in[1];
  const float* ew      = (const float*)d_in[2];
  const float* tsp     = (const float*)d_in[3];
  const float* w_enc   = (const float*)d_in[4];
  const float* b_enc   = (const float*)d_in[5];
  const float* g_enc   = (const float*)d_in[6];
  const float* be_enc  = (const float*)d_in[7];
  const float* w_time  = (const float*)d_in[8];
  const float* b_time  = (const float*)d_in[9];
  const float* g_time  = (const float*)d_in[10];
  const float* be_time = (const float*)d_in[11];
  const float* wm      = (const float*)d_in[12];
  const float* bm      = (const float*)d_in[13];
  const float* gm      = (const float*)d_in[14];
  const float* bem     = (const float*)d_in[15];
  const float* wu      = (const float*)d_in[16];
  const float* bu      = (const float*)d_in[17];
  const float* gu      = (const float*)d_in[18];
  const float* beu     = (const float*)d_in[19];
  const float* wg      = (const float*)d_in[20];
  const float* bg      = (const float*)d_in[21];
  const float* w_out   = (const float*)d_in[22];
  const float* b_out   = (const float*)d_in[23];
  float* out = (float*)d_out;

  // ws layout (bytes): h16 f16[NN*160] @0 (32M) | msum16 f16[NN*160] @32,000,000 (32M)
  //   P f16[NN*320] @64,000,000 (64M) | WuP @128,000,000 (204,800) | WoP @128,204,800 (40,960)
  char* ws = (char*)d_ws;
  _Float16* h16    = (_Float16*)ws;
  _Float16* msum16 = (_Float16*)(ws + 32000000);
  _Float16* P      = (_Float16*)(ws + 64000000);
  _Float16* WuP16  = (_Float16*)(ws + 128000000);
  _Float16* WoP16  = (_Float16*)(ws + 128204800);
  // d_out doubles as scratch; k_update_out reads only ws-resident scratch.
  char* ob = (char*)d_out;
  _Float16* WpP16 = (_Float16*)ob;            // 204,800
  _Float16* WeP16 = (_Float16*)(ob + 204800); // 32,768
  int* off    = (int*)(ob + 237568);          // 400,016
  int* cnti   = (int*)(ob + 637584);          // 400,000
  int* cursor = (int*)(ob + 1037584);         // 400,000
  int* bsum   = (int*)(ob + 1437584);         // 1,568
  int* bsum2  = (int*)(ob + 1439152);         // 1,568
  int2* selist = (int2*)(ob + 1440720);       // 6,400,000 -> 7,840,720 < 51,200,000

  // weight prep + CSR build (edges static across layers: build once)
  k_zero<<<dim3(98), dim3(256), 0, stream>>>((float4*)cnti, 25000);
  k_pack<<<dim3(118), dim3(256), 0, stream>>>(w_enc, w_out, wu, wm,
                                              WeP16, WoP16, WuP16, WpP16);
  k_count_i<<<dim3(3125), dim3(256), 0, stream>>>(ei, cnti);
  k_scan1<<<dim3(391), dim3(256), 0, stream>>>(cnti, off, bsum);
  k_scan2<<<dim3(1), dim3(512), 0, stream>>>(bsum, bsum2);
  k_scan3<<<dim3(391), dim3(256), 0, stream>>>(off, bsum2, cursor);
  k_scatter<<<dim3(3125), dim3(256), 0, stream>>>(ei, ew, cursor, selist);

  k_encode_proj<<<dim3(6250), dim3(64), 0, stream>>>(
      x, tsp, WeP16, b_enc, g_enc, be_enc, w_time, b_time, g_time, be_time,
      WpP16, bm, h16, P);
  k_edge5<<<dim3(12500), dim3(256), 0, stream>>>(P, off, selist, gm, bem, msum16);
  k_update_proj<<<dim3(6250), dim3(64), 0, stream>>>(
      h16, msum16, WuP16, bu, gu, beu, wg, bg,
      WpP16 + 51200, bm + 160, P);
  k_edge5<<<dim3(12500), dim3(256), 0, stream>>>(P, off, selist, gm + 160, bem + 160, msum16);
  k_update_out<<<dim3(6250), dim3(64), 0, stream>>>(
      h16, msum16, WuP16 + 51200, bu + 160, gu + 160, beu + 160, wg + 160, bg + 1,
      WoP16, b_out, out);
}